// Round 1
// baseline (1565.667 us; speedup 1.0000x reference)
//
#include <hip/hip_runtime.h>
#include <stdint.h>

// Problem constants (from reference)
#define B_DIM 4
#define T_DIM 512
#define NTOK  2048          // B*T
#define H_DIM 2048
#define V_DIM 32000
#define TM    128
#define TN    128
#define BK    64            // two 32-deep MFMA phases per barrier pair
#define NCHUNK (V_DIM / TN) // 250
#define NTILE  (NTOK / TM)  // 16
#define BETA   0.1f
#define IGNORE_INDEX (-100)

typedef _Float16 f16;
typedef _Float16 half8 __attribute__((ext_vector_type(8)));
typedef float    f32x4 __attribute__((ext_vector_type(4)));

// ---------------------------------------------------------------- fp32 -> fp16
__global__ __launch_bounds__(256) void cvt_f32_f16(const float* __restrict__ src,
                                                   f16* __restrict__ dst, int n) {
    int i = (blockIdx.x * 256 + threadIdx.x) * 8;
    if (i + 8 > n) return;
    float4 v0 = *(const float4*)(src + i);
    float4 v1 = *(const float4*)(src + i + 4);
    half8 h = { (f16)v0.x, (f16)v0.y, (f16)v0.z, (f16)v0.w,
                (f16)v1.x, (f16)v1.y, (f16)v1.z, (f16)v1.w };
    *(half8*)(dst + i) = h;
}

// ---------------------------------------------------------------- GEMM + online LSE partials
// C[m][n] = sum_k X[m][k] * W[n][k]   (NT gemm, both row-major, K contiguous)
// LDS tile layout: [kchunk(8)][row(128)][8 halves]; fragment reads by a quad
// group touch 16 contiguous 16B cells (bank-conflict-free, verified R2).
// BK=64: 32 barrier pairs instead of 64 — halves the vmcnt(0) drain count
// (the dominant stall: W is 262MB, loads are HBM-latency).
template <bool DIRECT>
__global__ __launch_bounds__(256, 3) void gemm_lse(
    const void* __restrict__ x0, const void* __restrict__ x1,
    const void* __restrict__ w0, const void* __restrict__ w1,
    const int* __restrict__ y,
    float2* __restrict__ pMS,
    float* __restrict__ tokL)
{
    const int tile  = blockIdx.x;   // 0..15  (fastest: 16 tiles share one W chunk in LLC)
    const int chunk = blockIdx.y;   // 0..249
    const int model = blockIdx.z;   // 0..1
    const void* Xp = model ? x1 : x0;
    const void* Wp = model ? w1 : w0;

    const int tid  = threadIdx.x;
    const int lane = tid & 63;
    const int wave = tid >> 6;
    const int wm   = wave >> 1;     // 0..1: which 64-row half (tokens)
    const int wn   = wave & 1;      // 0..1: which 64-col half (vocab)

    __shared__ __align__(16) f16 As[8][TM][8];  // 16 KB  [kchunk][row][8]
    __shared__ __align__(16) f16 Bs[8][TN][8];  // 16 KB
    __shared__ float redM[TM][2];
    __shared__ float redS[TM][2];
    __shared__ int   ys[TM];

    if (tid < TM) ys[tid] = y[tile * TM + tid];

    f32x4 acc[4][4];
#pragma unroll
    for (int i = 0; i < 4; ++i)
#pragma unroll
        for (int j = 0; j < 4; ++j) acc[i][j] = (f32x4){0.f, 0.f, 0.f, 0.f};

    const int rowA0 = tile * TM;
    const int rowB0 = chunk * TN;
    const int kc    = lane >> 4;    // k-chunk (0..3) within a 32-deep phase

    // Staging map: load i covers LDS slot idx=i*256+tid -> chunk c=idx>>7, row r=idx&127.
    // r = tid&127 is i-invariant; c = i*2 + (tid>>7). So one base pointer per
    // matrix + constant immediate offsets (i*16 halves src, i*2048 halves dst).
    const int rS = tid & 127;
    const int cS = tid >> 7;

    if (DIRECT) {
        const f16* pA = (const f16*)Xp + (size_t)(rowA0 + rS) * H_DIM + cS * 8;
        const f16* pB = (const f16*)Wp + (size_t)(rowB0 + rS) * H_DIM + cS * 8;
        f16* dA = &As[0][0][0] + tid * 8;
        f16* dB = &Bs[0][0][0] + tid * 8;

        for (int k0 = 0; k0 < H_DIM; k0 += BK) {
#pragma unroll
            for (int i = 0; i < 4; ++i)
                __builtin_amdgcn_global_load_lds(
                    (const __attribute__((address_space(1))) unsigned int*)(pA + i * 16),
                    (__attribute__((address_space(3))) unsigned int*)(dA + i * 2048),
                    16, 0, 0);
#pragma unroll
            for (int i = 0; i < 4; ++i)
                __builtin_amdgcn_global_load_lds(
                    (const __attribute__((address_space(1))) unsigned int*)(pB + i * 16),
                    (__attribute__((address_space(3))) unsigned int*)(dB + i * 2048),
                    16, 0, 0);
            pA += BK; pB += BK;
            __syncthreads();

#pragma unroll
            for (int p = 0; p < 2; ++p) {
                half8 af[4], bfr[4];
#pragma unroll
                for (int i = 0; i < 4; ++i)
                    af[i] = *(const half8*)As[p * 4 + kc][wm * 64 + i * 16 + (lane & 15)];
#pragma unroll
                for (int j = 0; j < 4; ++j)
                    bfr[j] = *(const half8*)Bs[p * 4 + kc][wn * 64 + j * 16 + (lane & 15)];
#pragma unroll
                for (int i = 0; i < 4; ++i)
#pragma unroll
                    for (int j = 0; j < 4; ++j)
                        acc[i][j] = __builtin_amdgcn_mfma_f32_16x16x32_f16(af[i], bfr[j], acc[i][j], 0, 0, 0);
            }
            __syncthreads();
        }
    } else {
        const float* pA = (const float*)Xp + (size_t)(rowA0 + rS) * H_DIM + cS * 8;
        const float* pB = (const float*)Wp + (size_t)(rowB0 + rS) * H_DIM + cS * 8;
        f16* dA = &As[0][0][0] + tid * 8;
        f16* dB = &Bs[0][0][0] + tid * 8;

        for (int k0 = 0; k0 < H_DIM; k0 += BK) {
#pragma unroll
            for (int i = 0; i < 4; ++i) {
                float4 v0 = *(const float4*)(pA + i * 16);
                float4 v1 = *(const float4*)(pA + i * 16 + 4);
                half8 h = { (f16)v0.x, (f16)v0.y, (f16)v0.z, (f16)v0.w,
                            (f16)v1.x, (f16)v1.y, (f16)v1.z, (f16)v1.w };
                *(half8*)(dA + i * 2048) = h;
            }
#pragma unroll
            for (int i = 0; i < 4; ++i) {
                float4 v0 = *(const float4*)(pB + i * 16);
                float4 v1 = *(const float4*)(pB + i * 16 + 4);
                half8 h = { (f16)v0.x, (f16)v0.y, (f16)v0.z, (f16)v0.w,
                            (f16)v1.x, (f16)v1.y, (f16)v1.z, (f16)v1.w };
                *(half8*)(dB + i * 2048) = h;
            }
            pA += BK; pB += BK;
            __syncthreads();

#pragma unroll
            for (int p = 0; p < 2; ++p) {
                half8 af[4], bfr[4];
#pragma unroll
                for (int i = 0; i < 4; ++i)
                    af[i] = *(const half8*)As[p * 4 + kc][wm * 64 + i * 16 + (lane & 15)];
#pragma unroll
                for (int j = 0; j < 4; ++j)
                    bfr[j] = *(const half8*)Bs[p * 4 + kc][wn * 64 + j * 16 + (lane & 15)];
#pragma unroll
                for (int i = 0; i < 4; ++i)
#pragma unroll
                    for (int j = 0; j < 4; ++j)
                        acc[i][j] = __builtin_amdgcn_mfma_f32_16x16x32_f16(af[i], bfr[j], acc[i][j], 0, 0, 0);
            }
            __syncthreads();
        }
    }

    // ---- epilogue ----
    // C/D layout: col = lane&15 (vocab), row = (lane>>4)*4 + reg (token)
    // 1) target logit — ALL acc indices compile-time constant (R1 scratch bug)
#pragma unroll
    for (int i = 0; i < 4; ++i) {
#pragma unroll
        for (int r = 0; r < 4; ++r) {
            int rl = wm * 64 + i * 16 + ((lane >> 4) << 2) + r;
            int t = ys[rl];
            int trel = t - (rowB0 + wn * 64);
#pragma unroll
            for (int j = 0; j < 4; ++j) {
                if (trel == j * 16 + (lane & 15))
                    tokL[model * NTOK + rowA0 + rl] = acc[i][j][r];
            }
        }
    }

    // 2) per-row (max, sumexp) over this wave's 64 columns, then combine halves
#pragma unroll
    for (int i = 0; i < 4; ++i) {
#pragma unroll
        for (int r = 0; r < 4; ++r) {
            float mx = fmaxf(fmaxf(acc[i][0][r], acc[i][1][r]),
                             fmaxf(acc[i][2][r], acc[i][3][r]));
            for (int m = 1; m < 16; m <<= 1) mx = fmaxf(mx, __shfl_xor(mx, m, 64));
            float s = 0.f;
#pragma unroll
            for (int j = 0; j < 4; ++j) s += __expf(acc[i][j][r] - mx);
            for (int m = 1; m < 16; m <<= 1) s += __shfl_xor(s, m, 64);
            if ((lane & 15) == 0) {
                int rl = wm * 64 + i * 16 + ((lane >> 4) << 2) + r;
                redM[rl][wn] = mx;
                redS[rl][wn] = s;
            }
        }
    }
    __syncthreads();
    if (tid < TM) {
        float m0 = redM[tid][0], m1 = redM[tid][1];
        float s0 = redS[tid][0], s1 = redS[tid][1];
        float M = fmaxf(m0, m1);
        float S = s0 * __expf(m0 - M) + s1 * __expf(m1 - M);
        // transposed partials: [model][token][chunk] for coalesced lse_reduce
        size_t o = ((size_t)model * NTOK + rowA0 + tid) * NCHUNK + chunk;
        pMS[o] = make_float2(M, S);
    }
}

// ---------------------------------------------------------------- combine chunk partials -> per-token logp
// One wave per (model,token): coalesced 2KB read + wave-level LSE merge.
__global__ __launch_bounds__(256) void lse_reduce(const float2* __restrict__ pMS,
                                                  const float* __restrict__ tokL,
                                                  const int* __restrict__ y,
                                                  float* __restrict__ logp) {
    int g = blockIdx.x * 4 + (threadIdx.x >> 6);   // 0..4095 = model*NTOK + token
    int lane = threadIdx.x & 63;
    const float2* base = pMS + (size_t)g * NCHUNK;
    float M = -1e30f, S = 0.f;
    for (int c = lane; c < NCHUNK; c += 64) {
        float2 ms = base[c];
        if (ms.x > M) { S = S * __expf(M - ms.x) + ms.y; M = ms.x; }
        else          { S += ms.y * __expf(ms.x - M); }
    }
#pragma unroll
    for (int off = 1; off < 64; off <<= 1) {
        float Mo = __shfl_xor(M, off, 64);
        float So = __shfl_xor(S, off, 64);
        float Mn = fmaxf(M, Mo);
        S = S * __expf(M - Mn) + So * __expf(Mo - Mn);
        M = Mn;
    }
    if (lane == 0) {
        float lse = M + logf(S);
        int token = g & (NTOK - 1);
        int t = y[token];
        logp[g] = (t == IGNORE_INDEX) ? 0.f : (tokL[g] - lse);
    }
}

// ---------------------------------------------------------------- final KTO scalar
__device__ __forceinline__ float sigf(float z) { return 1.f / (1.f + expf(-z)); }

__global__ void final_loss(const float* __restrict__ logp,
                           const int* __restrict__ y,
                           float* __restrict__ out) {
    int lane = threadIdx.x;  // 64 threads, one wave
    float avg[2][4];
    for (int model = 0; model < 2; ++model)
        for (int b = 0; b < 4; ++b) {
            float s = 0.f, c = 0.f;
            for (int t = lane; t < T_DIM; t += 64) {
                int token = b * T_DIM + t;
                if (y[token] != IGNORE_INDEX) { s += logp[model * NTOK + token]; c += 1.f; }
            }
            for (int m = 1; m < 64; m <<= 1) {
                s += __shfl_xor(s, m, 64);
                c += __shfl_xor(c, m, 64);
            }
            avg[model][b] = s / c;
        }
    if (lane == 0) {
        float loss = 0.f;
        for (int b = 0; b < 2; ++b) {                    // chosen
            float lr = avg[0][b] - avg[1][b];
            loss += 1.f - sigf(BETA * lr);
        }
        for (int b = 2; b < 4; ++b) {                    // rejected
            float lr = avg[0][b] - avg[1][b];
            loss += 1.f - sigf(-BETA * lr);
        }
        out[0] = loss * 0.5f;                            // / half (half = 2)
    }
}

// ---------------------------------------------------------------- launch
extern "C" void kernel_launch(void* const* d_in, const int* in_sizes, int n_in,
                              void* d_out, int out_size, void* d_ws, size_t ws_size,
                              hipStream_t stream) {
    const float* x  = (const float*)d_in[0];
    const float* rx = (const float*)d_in[1];
    const int*   y  = (const int*)d_in[2];
    const float* W  = (const float*)d_in[3];
    const float* rW = (const float*)d_in[4];
    float* out = (float*)d_out;

    const size_t nX = (size_t)NTOK * H_DIM;   // 4,194,304
    const size_t nW = (size_t)V_DIM * H_DIM;  // 65,536,000

    char* p = (char*)d_ws;
    float2* pMS = (float2*)p; p += (size_t)2 * NTOK * NCHUNK * 8;   // 16.4 MB
    float* tokL = (float*)p;  p += (size_t)2 * NTOK * 4;
    float* logp = (float*)p;  p += (size_t)2 * NTOK * 4;
    size_t base = (size_t)(p - (char*)d_ws);
    size_t need_fast = base + 2 * nX * 2 + 2 * nW * 2;

    dim3 grid(NTILE, NCHUNK, 2);
    if (ws_size >= need_fast) {
        f16* xb  = (f16*)p; p += nX * 2;
        f16* rxb = (f16*)p; p += nX * 2;
        f16* wb  = (f16*)p; p += nW * 2;
        f16* rwb = (f16*)p; p += nW * 2;
        cvt_f32_f16<<<(int)(nX / 8 / 256), 256, 0, stream>>>(x,  xb,  (int)nX);
        cvt_f32_f16<<<(int)(nX / 8 / 256), 256, 0, stream>>>(rx, rxb, (int)nX);
        cvt_f32_f16<<<(int)(nW / 8 / 256), 256, 0, stream>>>(W,  wb,  (int)nW);
        cvt_f32_f16<<<(int)(nW / 8 / 256), 256, 0, stream>>>(rW, rwb, (int)nW);
        gemm_lse<true><<<grid, 256, 0, stream>>>(xb, rxb, wb, rwb, y, pMS, tokL);
    } else {
        gemm_lse<false><<<grid, 256, 0, stream>>>(x, rx, W, rW, y, pMS, tokL);
    }
    lse_reduce<<<1024, 256, 0, stream>>>(pMS, tokL, y, logp);
    final_loss<<<1, 64, 0, stream>>>(logp, y, out);
}

// Round 2
// 1409.566 us; speedup vs baseline: 1.1107x; 1.1107x over previous
//
#include <hip/hip_runtime.h>
#include <stdint.h>

// Problem constants (from reference)
#define B_DIM 4
#define T_DIM 512
#define NTOK  2048          // B*T
#define H_DIM 2048
#define V_DIM 32000
#define BETA   0.1f
#define IGNORE_INDEX (-100)

// fallback (fp32-input) tile
#define TM    128
#define TN    128
#define BK    64
#define NCHUNK 250          // fallback chunks
// 8-phase kernel tile
#define NCH8  125           // V/256
#define NTILE8 8            // NTOK/256

typedef _Float16 f16;
typedef _Float16 half8 __attribute__((ext_vector_type(8)));
typedef float    f32x4 __attribute__((ext_vector_type(4)));

#define AS1(p) ((const __attribute__((address_space(1))) unsigned int*)(p))
#define AS3(p) ((__attribute__((address_space(3))) unsigned int*)(p))

// ---------------------------------------------------------------- fp32 -> fp16
__global__ __launch_bounds__(256) void cvt_f32_f16(const float* __restrict__ src,
                                                   f16* __restrict__ dst, int n) {
    int i = (blockIdx.x * 256 + threadIdx.x) * 8;
    if (i + 8 > n) return;
    float4 v0 = *(const float4*)(src + i);
    float4 v1 = *(const float4*)(src + i + 4);
    half8 h = { (f16)v0.x, (f16)v0.y, (f16)v0.z, (f16)v0.w,
                (f16)v1.x, (f16)v1.y, (f16)v1.z, (f16)v1.w };
    *(half8*)(dst + i) = h;
}

// ================================================================ 8-phase 256^2 GEMM + LSE
// 256x256 tile, BK=64, 512 thr / 8 waves (2x4), 2 double-buffered K-tile LDS
// buffers, [kc][row][8] micro-layout (measured conflict-free in R1).
// Schedule: T3+T4 counted-vmcnt 8-phase (guide §5 template), T5 setprio,
// T1 XCD-bijective swizzle (2000 % 8 == 0).
//
// Phase = (BUF, KH=k-half of 64, FH=row-half of the wave's 8 m-frags).
// Stage unit = half-tile = (matrix, k-half) = 2 x global_load_lds / thread.
// Ledger (per-wave vmcnt instruction counts, steady state):
//   start of iter: 4 outstanding (prev P7,P8 = b1kh0 of kt 2i+1)
//   P1,P2 stage b1kh1(kt 2i+1); P3,P4 stage b0kh0(kt 2i+2) -> 12
//   vmcnt(4) @P4-end: drains prev-b1kh0 (read P5,P6) + b1kh1 (read P7,P8) OK
//   P5,P6 stage b0kh1(kt 2i+2); P7,P8 stage b1kh0(kt 2i+3) -> 12
//   vmcnt(4) @P8-end: drains b0kh0+b0kh1 (read next P1..P4) OK -> invariant 4.
// Overwrite safety: each stage target's last ds_read is >=1 closing s_barrier
// earlier (b1kh1: prev P7P8 reads; b0kh0: P1P2; b0kh1: P3P4; b1kh0: P5P6).
// Last iter (i=15) stages kt 32,33 wrapped &31 -> in-bounds garbage, never read.

#define DSR_(d, a, OFFSTR) \
    asm volatile("ds_read_b128 %0, %1 offset:" OFFSTR : "=v"(d) : "v"(a))

#define VM4    asm volatile("s_waitcnt vmcnt(4)" ::: "memory")
#define VMNONE ((void)0)

#define STAGE(MAT, BUF, KH, KT, PTR) do {                                      \
    const f16* s_ = (PTR) + (((KT) & 31) << 6) + (KH) * 32;                    \
    f16* d_ = dBase + (BUF) * 32768 + (MAT) * 16384 + (KH) * 8192;             \
    __builtin_amdgcn_global_load_lds(AS1(s_),      AS3(d_),        16, 0, 0);  \
    __builtin_amdgcn_global_load_lds(AS1(s_ + 16), AS3(d_ + 4096), 16, 0, 0);  \
} while (0)

#define PHASE(BUF, KH, FH, WAITV, ...) do {                                    \
    half8 af[4];                                                               \
    unsigned aAd = A_rd + ((BUF) * 65536u + (KH) * 16384u + (FH) * 1024u);     \
    DSR_(af[0], aAd, "0");   DSR_(af[1], aAd, "256");                          \
    DSR_(af[2], aAd, "512"); DSR_(af[3], aAd, "768");                          \
    if ((FH) == 0) {                                                           \
        unsigned bAd = B_rd + ((BUF) * 65536u + (KH) * 16384u);                \
        DSR_(bfp[0], bAd, "0");   DSR_(bfp[1], bAd, "256");                    \
        DSR_(bfp[2], bAd, "512"); DSR_(bfp[3], bAd, "768");                    \
    }                                                                          \
    __VA_ARGS__;                                                               \
    __builtin_amdgcn_sched_barrier(0);                                         \
    __builtin_amdgcn_s_barrier();                                              \
    __builtin_amdgcn_sched_barrier(0);                                         \
    asm volatile("s_waitcnt lgkmcnt(0)" ::: "memory");                         \
    __builtin_amdgcn_sched_barrier(0);                                         \
    __builtin_amdgcn_s_setprio(1);                                             \
    _Pragma("unroll")                                                          \
    for (int m_ = 0; m_ < 4; ++m_) {                                           \
        _Pragma("unroll")                                                      \
        for (int n_ = 0; n_ < 4; ++n_)                                         \
            acc[(FH) * 4 + m_][n_] = __builtin_amdgcn_mfma_f32_16x16x32_f16(   \
                af[m_], bfp[n_], acc[(FH) * 4 + m_][n_], 0, 0, 0);             \
    }                                                                          \
    __builtin_amdgcn_s_setprio(0);                                             \
    __builtin_amdgcn_sched_barrier(0);                                         \
    WAITV;                                                                     \
    __builtin_amdgcn_s_barrier();                                              \
    __builtin_amdgcn_sched_barrier(0);                                         \
} while (0)

__global__ __launch_bounds__(512, 2) void gemm_lse8(
    const f16* __restrict__ x0, const f16* __restrict__ x1,
    const f16* __restrict__ w0, const f16* __restrict__ w1,
    const int* __restrict__ y,
    float2* __restrict__ pMS,
    float* __restrict__ tokL)
{
    // XCD-bijective swizzle: 2000 wgs, 2000 % 8 == 0 -> each XCD gets a
    // contiguous 250-wg slice (sequential W-chunk streaming per XCD L2).
    const int orig = blockIdx.x;
    const int wg   = (orig & 7) * 250 + (orig >> 3);
    const int tile = wg & 7;            // 0..7  (8 token tiles, fastest)
    const int rest = wg >> 3;           // 0..249
    const int chunk = rest % NCH8;      // 0..124
    const int model = rest / NCH8;      // 0..1

    const f16* Xp = model ? x1 : x0;
    const f16* Wp = model ? w1 : w0;

    const int tid  = threadIdx.x;
    const int lane = tid & 63;
    const int wave = tid >> 6;
    const int wm   = wave >> 2;         // 0..1: 128-row half (tokens)
    const int wn   = wave & 3;          // 0..3: 64-col quarter (vocab)

    // [buf][mat][kc][row][8] f16 = 128 KiB
    __shared__ __align__(16) f16 sm[2][2][8][256][8];
    __shared__ float redM[256][4];
    __shared__ float redS[256][4];
    __shared__ int   ys[256];

    const int rowA0 = tile * 256;
    const int rowB0 = chunk * 256;

    f32x4 acc[8][4];
#pragma unroll
    for (int i = 0; i < 8; ++i)
#pragma unroll
        for (int j = 0; j < 4; ++j) acc[i][j] = (f32x4){0.f, 0.f, 0.f, 0.f};

    // staging map: thread covers row rS, k-chunk-offset cS (16B per load)
    const int rS = tid & 255;
    const int cS = tid >> 8;            // 0..1
    const f16* pA = Xp + (size_t)(rowA0 + rS) * H_DIM + cS * 8;
    const f16* pB = Wp + (size_t)(rowB0 + rS) * H_DIM + cS * 8;
    f16* dBase = &sm[0][0][0][0][0] + (size_t)tid * 8;

    // fragment-read LDS byte bases (proven-conflict-free pattern from R1)
    auto* smp3 = (__attribute__((address_space(3))) f16*)&sm[0][0][0][0][0];
    const unsigned smBase = (unsigned)(uintptr_t)smp3;
    const unsigned A_rd = smBase + ((unsigned)(lane >> 4) << 12)
                        + (((unsigned)(wm * 128 + (lane & 15))) << 4);
    const unsigned B_rd = smBase + 32768u + ((unsigned)(lane >> 4) << 12)
                        + (((unsigned)(wn * 64 + (lane & 15))) << 4);

    half8 bfp[4];   // B frags persist across the FH0/FH1 phase pair

    // ---- prologue: y load (drained before ledger starts), stage kt0 + kt1.kh0
    int yreg = 0;
    if (tid < 256) yreg = y[rowA0 + tid];
    asm volatile("s_waitcnt vmcnt(0)" ::: "memory");
    __builtin_amdgcn_sched_barrier(0);

    STAGE(0, 0, 0, 0, pA); STAGE(1, 0, 0, 0, pB);
    STAGE(0, 0, 1, 0, pA); STAGE(1, 0, 1, 0, pB);
    STAGE(0, 1, 0, 1, pA); STAGE(1, 1, 0, 1, pB);
    asm volatile("s_waitcnt vmcnt(4)" ::: "memory");   // kt0 (b0) complete
    __builtin_amdgcn_sched_barrier(0);
    __builtin_amdgcn_s_barrier();
    __builtin_amdgcn_sched_barrier(0);
    if (tid < 256) ys[tid] = yreg;

    // ---- main loop: 16 iters x 8 phases (2 K-tiles / iter)
#pragma unroll 1
    for (int i = 0; i < 16; ++i) {
        const int kt1 = 2 * i + 1, kt2 = 2 * i + 2, kt3 = 2 * i + 3;
        PHASE(0, 0, 0, VMNONE, STAGE(0, 1, 1, kt1, pA));
        PHASE(0, 0, 1, VMNONE, STAGE(1, 1, 1, kt1, pB));
        PHASE(0, 1, 0, VMNONE, STAGE(0, 0, 0, kt2, pA));
        PHASE(0, 1, 1, VM4,    STAGE(1, 0, 0, kt2, pB));
        PHASE(1, 0, 0, VMNONE, STAGE(0, 0, 1, kt2, pA));
        PHASE(1, 0, 1, VMNONE, STAGE(1, 0, 1, kt2, pB));
        PHASE(1, 1, 0, VMNONE, STAGE(0, 1, 0, kt3, pA));
        PHASE(1, 1, 1, VM4,    STAGE(1, 1, 0, kt3, pB));
    }

    // ---- epilogue ----
    __syncthreads();   // drains tail garbage stages; orders ys for all waves

    // C/D layout: col = lane&15 (vocab), row = (lane>>4)*4 + reg (token)
    // 1) target logit — all acc indices compile-time constant
#pragma unroll
    for (int i2 = 0; i2 < 8; ++i2) {
#pragma unroll
        for (int r = 0; r < 4; ++r) {
            int rl = wm * 128 + i2 * 16 + ((lane >> 4) << 2) + r;
            int t = ys[rl];
            int trel = t - (rowB0 + wn * 64);
#pragma unroll
            for (int j = 0; j < 4; ++j) {
                if (trel == j * 16 + (lane & 15))
                    tokL[model * NTOK + rowA0 + rl] = acc[i2][j][r];
            }
        }
    }

    // 2) per-row (max, sumexp) over this wave's 64 columns
#pragma unroll
    for (int i2 = 0; i2 < 8; ++i2) {
#pragma unroll
        for (int r = 0; r < 4; ++r) {
            float mx = fmaxf(fmaxf(acc[i2][0][r], acc[i2][1][r]),
                             fmaxf(acc[i2][2][r], acc[i2][3][r]));
            for (int m = 1; m < 16; m <<= 1) mx = fmaxf(mx, __shfl_xor(mx, m, 64));
            float s = 0.f;
#pragma unroll
            for (int j = 0; j < 4; ++j) s += __expf(acc[i2][j][r] - mx);
            for (int m = 1; m < 16; m <<= 1) s += __shfl_xor(s, m, 64);
            if ((lane & 15) == 0) {
                int rl = wm * 128 + i2 * 16 + ((lane >> 4) << 2) + r;
                redM[rl][wn] = mx;
                redS[rl][wn] = s;
            }
        }
    }
    __syncthreads();
    if (tid < 256) {
        float M = redM[tid][0], S = redS[tid][0];
#pragma unroll
        for (int q = 1; q < 4; ++q) {
            float m2 = redM[tid][q], s2 = redS[tid][q];
            float Mn = fmaxf(M, m2);
            S = S * __expf(M - Mn) + s2 * __expf(m2 - Mn);
            M = Mn;
        }
        size_t o = ((size_t)model * NTOK + rowA0 + tid) * NCH8 + chunk;
        pMS[o] = make_float2(M, S);
    }
}

// ================================================================ fallback fp32-input GEMM (R1-proven)
__global__ __launch_bounds__(256, 3) void gemm_lse_f32(
    const float* __restrict__ x0, const float* __restrict__ x1,
    const float* __restrict__ w0, const float* __restrict__ w1,
    const int* __restrict__ y,
    float2* __restrict__ pMS,
    float* __restrict__ tokL)
{
    const int tile  = blockIdx.x;
    const int chunk = blockIdx.y;
    const int model = blockIdx.z;
    const float* Xp = model ? x1 : x0;
    const float* Wp = model ? w1 : w0;

    const int tid  = threadIdx.x;
    const int lane = tid & 63;
    const int wave = tid >> 6;
    const int wm   = wave >> 1;
    const int wn   = wave & 1;

    __shared__ __align__(16) f16 As[8][TM][8];
    __shared__ __align__(16) f16 Bs[8][TN][8];
    __shared__ float redM[TM][2];
    __shared__ float redS[TM][2];
    __shared__ int   ys[TM];

    if (tid < TM) ys[tid] = y[tile * TM + tid];

    f32x4 acc[4][4];
#pragma unroll
    for (int i = 0; i < 4; ++i)
#pragma unroll
        for (int j = 0; j < 4; ++j) acc[i][j] = (f32x4){0.f, 0.f, 0.f, 0.f};

    const int rowA0 = tile * TM;
    const int rowB0 = chunk * TN;
    const int kc    = lane >> 4;
    const int rS = tid & 127;
    const int cS = tid >> 7;

    const float* pA = Xp + (size_t)(rowA0 + rS) * H_DIM + cS * 8;
    const float* pB = Wp + (size_t)(rowB0 + rS) * H_DIM + cS * 8;
    f16* dA = &As[0][0][0] + tid * 8;
    f16* dB = &Bs[0][0][0] + tid * 8;

    for (int k0 = 0; k0 < H_DIM; k0 += BK) {
#pragma unroll
        for (int i = 0; i < 4; ++i) {
            float4 v0 = *(const float4*)(pA + i * 16);
            float4 v1 = *(const float4*)(pA + i * 16 + 4);
            half8 h = { (f16)v0.x, (f16)v0.y, (f16)v0.z, (f16)v0.w,
                        (f16)v1.x, (f16)v1.y, (f16)v1.z, (f16)v1.w };
            *(half8*)(dA + i * 2048) = h;
        }
#pragma unroll
        for (int i = 0; i < 4; ++i) {
            float4 v0 = *(const float4*)(pB + i * 16);
            float4 v1 = *(const float4*)(pB + i * 16 + 4);
            half8 h = { (f16)v0.x, (f16)v0.y, (f16)v0.z, (f16)v0.w,
                        (f16)v1.x, (f16)v1.y, (f16)v1.z, (f16)v1.w };
            *(half8*)(dB + i * 2048) = h;
        }
        pA += BK; pB += BK;
        __syncthreads();

#pragma unroll
        for (int p = 0; p < 2; ++p) {
            half8 af[4], bfr[4];
#pragma unroll
            for (int i = 0; i < 4; ++i)
                af[i] = *(const half8*)As[p * 4 + kc][wm * 64 + i * 16 + (lane & 15)];
#pragma unroll
            for (int j = 0; j < 4; ++j)
                bfr[j] = *(const half8*)Bs[p * 4 + kc][wn * 64 + j * 16 + (lane & 15)];
#pragma unroll
            for (int i = 0; i < 4; ++i)
#pragma unroll
                for (int j = 0; j < 4; ++j)
                    acc[i][j] = __builtin_amdgcn_mfma_f32_16x16x32_f16(af[i], bfr[j], acc[i][j], 0, 0, 0);
        }
        __syncthreads();
    }

#pragma unroll
    for (int i = 0; i < 4; ++i) {
#pragma unroll
        for (int r = 0; r < 4; ++r) {
            int rl = wm * 64 + i * 16 + ((lane >> 4) << 2) + r;
            int t = ys[rl];
            int trel = t - (rowB0 + wn * 64);
#pragma unroll
            for (int j = 0; j < 4; ++j) {
                if (trel == j * 16 + (lane & 15))
                    tokL[model * NTOK + rowA0 + rl] = acc[i][j][r];
            }
        }
    }

#pragma unroll
    for (int i = 0; i < 4; ++i) {
#pragma unroll
        for (int r = 0; r < 4; ++r) {
            float mx = fmaxf(fmaxf(acc[i][0][r], acc[i][1][r]),
                             fmaxf(acc[i][2][r], acc[i][3][r]));
            for (int m = 1; m < 16; m <<= 1) mx = fmaxf(mx, __shfl_xor(mx, m, 64));
            float s = 0.f;
#pragma unroll
            for (int j = 0; j < 4; ++j) s += __expf(acc[i][j][r] - mx);
            for (int m = 1; m < 16; m <<= 1) s += __shfl_xor(s, m, 64);
            if ((lane & 15) == 0) {
                int rl = wm * 64 + i * 16 + ((lane >> 4) << 2) + r;
                redM[rl][wn] = mx;
                redS[rl][wn] = s;
            }
        }
    }
    __syncthreads();
    if (tid < TM) {
        float m0 = redM[tid][0], m1 = redM[tid][1];
        float s0 = redS[tid][0], s1 = redS[tid][1];
        float M = fmaxf(m0, m1);
        float S = s0 * __expf(m0 - M) + s1 * __expf(m1 - M);
        size_t o = ((size_t)model * NTOK + tile * TM + tid) * NCHUNK + chunk;
        pMS[o] = make_float2(M, S);
    }
}

// ---------------------------------------------------------------- combine chunk partials -> per-token logp
__global__ __launch_bounds__(256) void lse_reduce(const float2* __restrict__ pMS,
                                                  const float* __restrict__ tokL,
                                                  const int* __restrict__ y,
                                                  float* __restrict__ logp,
                                                  int nchunk) {
    int g = blockIdx.x * 4 + (threadIdx.x >> 6);   // 0..4095 = model*NTOK + token
    int lane = threadIdx.x & 63;
    const float2* base = pMS + (size_t)g * nchunk;
    float M = -1e30f, S = 0.f;
    for (int c = lane; c < nchunk; c += 64) {
        float2 ms = base[c];
        if (ms.x > M) { S = S * __expf(M - ms.x) + ms.y; M = ms.x; }
        else          { S += ms.y * __expf(ms.x - M); }
    }
#pragma unroll
    for (int off = 1; off < 64; off <<= 1) {
        float Mo = __shfl_xor(M, off, 64);
        float So = __shfl_xor(S, off, 64);
        float Mn = fmaxf(M, Mo);
        S = S * __expf(M - Mn) + So * __expf(Mo - Mn);
        M = Mn;
    }
    if (lane == 0) {
        float lse = M + logf(S);
        int token = g & (NTOK - 1);
        int t = y[token];
        logp[g] = (t == IGNORE_INDEX) ? 0.f : (tokL[g] - lse);
    }
}

// ---------------------------------------------------------------- final KTO scalar
__device__ __forceinline__ float sigf(float z) { return 1.f / (1.f + expf(-z)); }

__global__ void final_loss(const float* __restrict__ logp,
                           const int* __restrict__ y,
                           float* __restrict__ out) {
    int lane = threadIdx.x;  // 64 threads, one wave
    float avg[2][4];
    for (int model = 0; model < 2; ++model)
        for (int b = 0; b < 4; ++b) {
            float s = 0.f, c = 0.f;
            for (int t = lane; t < T_DIM; t += 64) {
                int token = b * T_DIM + t;
                if (y[token] != IGNORE_INDEX) { s += logp[model * NTOK + token]; c += 1.f; }
            }
            for (int m = 1; m < 64; m <<= 1) {
                s += __shfl_xor(s, m, 64);
                c += __shfl_xor(c, m, 64);
            }
            avg[model][b] = s / c;
        }
    if (lane == 0) {
        float loss = 0.f;
        for (int b = 0; b < 2; ++b) {
            float lr = avg[0][b] - avg[1][b];
            loss += 1.f - sigf(BETA * lr);
        }
        for (int b = 2; b < 4; ++b) {
            float lr = avg[0][b] - avg[1][b];
            loss += 1.f - sigf(-BETA * lr);
        }
        out[0] = loss * 0.5f;
    }
}

// ---------------------------------------------------------------- launch
extern "C" void kernel_launch(void* const* d_in, const int* in_sizes, int n_in,
                              void* d_out, int out_size, void* d_ws, size_t ws_size,
                              hipStream_t stream) {
    const float* x  = (const float*)d_in[0];
    const float* rx = (const float*)d_in[1];
    const int*   y  = (const int*)d_in[2];
    const float* W  = (const float*)d_in[3];
    const float* rW = (const float*)d_in[4];
    float* out = (float*)d_out;

    const size_t nX = (size_t)NTOK * H_DIM;   // 4,194,304
    const size_t nW = (size_t)V_DIM * H_DIM;  // 65,536,000

    char* p = (char*)d_ws;
    float2* pMS = (float2*)p; p += (size_t)2 * NTOK * NCHUNK * 8;   // sized for max stride
    float* tokL = (float*)p;  p += (size_t)2 * NTOK * 4;
    float* logp = (float*)p;  p += (size_t)2 * NTOK * 4;
    size_t base = (size_t)(p - (char*)d_ws);
    size_t need_fast = base + 2 * nX * 2 + 2 * nW * 2;

    if (ws_size >= need_fast) {
        f16* xb  = (f16*)p; p += nX * 2;
        f16* rxb = (f16*)p; p += nX * 2;
        f16* wb  = (f16*)p; p += nW * 2;
        f16* rwb = (f16*)p; p += nW * 2;
        cvt_f32_f16<<<(int)(nX / 8 / 256), 256, 0, stream>>>(x,  xb,  (int)nX);
        cvt_f32_f16<<<(int)(nX / 8 / 256), 256, 0, stream>>>(rx, rxb, (int)nX);
        cvt_f32_f16<<<(int)(nW / 8 / 256), 256, 0, stream>>>(W,  wb,  (int)nW);
        cvt_f32_f16<<<(int)(nW / 8 / 256), 256, 0, stream>>>(rW, rwb, (int)nW);
        gemm_lse8<<<dim3(NTILE8 * NCH8 * 2), 512, 0, stream>>>(xb, rxb, wb, rwb, y, pMS, tokL);
        lse_reduce<<<1024, 256, 0, stream>>>(pMS, tokL, y, logp, NCH8);
    } else {
        gemm_lse_f32<<<dim3(NTOK / TM, NCHUNK, 2), 256, 0, stream>>>(x, rx, W, rW, y, pMS, tokL);
        lse_reduce<<<1024, 256, 0, stream>>>(pMS, tokL, y, logp, NCHUNK);
    }
    final_loss<<<1, 64, 0, stream>>>(logp, y, out);
}